// Round 3
// baseline (224.359 us; speedup 1.0000x reference)
//
#include <hip/hip_runtime.h>
#include <math.h>

#define B_ 8
#define U_ 512
#define T_ 1024
#define H_ 512
#define D_ 128
#define K_ 10

#define NBLK 512
#define NTHR 256
#define UT 8      // u rows per block in attend phase (512 = B * U/UT)
#define TC 64     // t chunk size

// Grid-wide barrier. cnt/gen zeroed by hipMemsetAsync before each launch, so
// state is identical on every (graph-replayed) call. Agent-scope release on
// arrival writes back the XCD's L2; agent-scope acquire on the spin (and the
// post-spin path) invalidates stale lines -> cross-XCD data visibility.
__device__ __forceinline__ void grid_barrier(unsigned* cnt, unsigned* gen) {
    __threadfence();           // publish this block's stores (agent fence)
    __syncthreads();
    if (threadIdx.x == 0) {
        unsigned g0 = __hip_atomic_load(gen, __ATOMIC_ACQUIRE, __HIP_MEMORY_SCOPE_AGENT);
        unsigned old = __hip_atomic_fetch_add(cnt, 1u, __ATOMIC_ACQ_REL, __HIP_MEMORY_SCOPE_AGENT);
        if (old == NBLK - 1) {
            __hip_atomic_store(cnt, 0u, __ATOMIC_RELAXED, __HIP_MEMORY_SCOPE_AGENT);
            __hip_atomic_fetch_add(gen, 1u, __ATOMIC_ACQ_REL, __HIP_MEMORY_SCOPE_AGENT);
        } else {
            while (__hip_atomic_load(gen, __ATOMIC_ACQUIRE, __HIP_MEMORY_SCOPE_AGENT) == g0)
                __builtin_amdgcn_s_sleep(2);
        }
    }
    __syncthreads();
}

__global__ __launch_bounds__(NTHR, 2)
void fused_kernel(const float* __restrict__ h_t,
                  const float* __restrict__ ctx,
                  const float* __restrict__ mask,
                  const float* __restrict__ W,
                  const float* __restrict__ bias,
                  float* __restrict__ out,
                  float* __restrict__ alpha,
                  float* __restrict__ beta,
                  float* __restrict__ kinc,
                  unsigned* __restrict__ bars) {
    __shared__ float a_s[UT][K_], b_s[UT][K_], k_s[UT][K_];
    __shared__ float phi_s[UT][TC + 1];
    __shared__ float ctx_s[TC][D_];          // 32 KB
    __shared__ float red_lo[NTHR], red_hi[NTHR];

    int tid = threadIdx.x;
    int lane = tid & 63;
    int wav = (blockIdx.x << 2) | (tid >> 6);    // global wave id, 0..2047

    // ---------------- Phase A: p = exp(h_t @ W + b), 2 rows per wave --------
    {
        int half = lane >> 5;          // row select within wave
        int j = lane & 31;             // output column
        if (j < 3 * K_) {
            int row = 2 * wav + half;  // covers 0..4095 exactly
            const float4* h4 = (const float4*)(h_t + (size_t)row * H_);
            float acc = 0.f;
            #pragma unroll 2
            for (int i = 0; i < H_ / 4; ++i) {
                float4 hv = h4[i];     // broadcast within each half
                acc += hv.x * W[(4 * i + 0) * (3 * K_) + j];  // 30-lane coalesced
                acc += hv.y * W[(4 * i + 1) * (3 * K_) + j];
                acc += hv.z * W[(4 * i + 2) * (3 * K_) + j];
                acc += hv.w * W[(4 * i + 3) * (3 * K_) + j];
            }
            float p = __expf(acc + bias[j]);
            int k = j % K_;
            int which = j / K_;
            size_t idx = (size_t)row * K_ + k;
            if (which == 0)      alpha[idx] = p;
            else if (which == 1) beta[idx]  = p;
            else                 kinc[idx]  = 0.2f * p;
        }
    }
    grid_barrier(&bars[0], &bars[1]);

    // ---------------- Phase B: kappa = cumsum(kinc) over u, first 80 waves --
    if (wav < B_ * K_) {
        int b = wav / K_, k = wav % K_;
        int ubase = lane * 8;
        float v[8];
        float run = 0.f;
        #pragma unroll
        for (int i = 0; i < 8; ++i) {
            float x = kinc[((size_t)(b * U_) + ubase + i) * K_ + k];
            run += x;
            v[i] = run;
        }
        float tot = run;
        float x = tot;
        for (int d = 1; d < 64; d <<= 1) {
            float y = __shfl_up(x, d, 64);
            if (lane >= d) x += y;
        }
        float excl = x - tot;
        #pragma unroll
        for (int i = 0; i < 8; ++i)
            kinc[((size_t)(b * U_) + ubase + i) * K_ + k] = v[i] + excl;
    }
    grid_barrier(&bars[2], &bars[3]);

    // ---------------- Phase C: phi + masked matmul --------------------------
    int b = blockIdx.x >> 6;             // 8 batches
    int u0 = (blockIdx.x & 63) * UT;     // 64 u-tiles of 8

    float lo = 1e30f, hi = -1e30f;
    if (tid < UT * K_) {
        int u_l = tid / K_, k = tid % K_;
        size_t idx = ((size_t)(b * U_) + u0 + u_l) * K_ + k;
        float av = alpha[idx], bv = beta[idx], kv = kinc[idx];
        a_s[u_l][k] = av; b_s[u_l][k] = bv; k_s[u_l][k] = kv;
        float r = sqrtf(88.f / bv);      // f32 exp underflow radius
        lo = kv - r; hi = kv + r;
    }
    red_lo[tid] = lo; red_hi[tid] = hi;
    __syncthreads();
    for (int s = NTHR / 2; s > 0; s >>= 1) {
        if (tid < s) {
            red_lo[tid] = fminf(red_lo[tid], red_lo[tid + s]);
            red_hi[tid] = fmaxf(red_hi[tid], red_hi[tid + s]);
        }
        __syncthreads();
    }
    int t_begin = max(0, (int)floorf(red_lo[0]));
    int t_end   = min(T_, (int)ceilf(red_hi[0]) + 1);
    t_begin = (t_begin / TC) * TC;

    int u_l = tid >> 5;                  // 0..7
    int g   = tid & 31;                  // d block: 4g..4g+3
    float acc[4];
    #pragma unroll
    for (int i = 0; i < 4; ++i) acc[i] = 0.f;

    for (int t0 = t_begin; t0 < t_end; t0 += TC) {
        __syncthreads();
        // stage ctx chunk (coalesced float4)
        {
            const float4* src = (const float4*)(ctx + (((size_t)b * T_ + t0) * D_));
            float4* dst = (float4*)(&ctx_s[0][0]);
            #pragma unroll
            for (int i = 0; i < (TC * D_ / 4) / NTHR; ++i)
                dst[tid + NTHR * i] = src[tid + NTHR * i];
        }
        // phi: UT*TC = 512 values, 2 per thread
        #pragma unroll
        for (int i = 0; i < 2; ++i) {
            int lin = tid + NTHR * i;
            int uu = lin >> 6;           // wave-uniform -> broadcast param reads
            int tl = lin & 63;
            float tf = (float)(t0 + tl);
            float ph = 0.f;
            #pragma unroll
            for (int k = 0; k < K_; ++k) {
                float d = k_s[uu][k] - tf;
                float x = b_s[uu][k] * d * d;
                ph += a_s[uu][k] * __expf(-x);
            }
            phi_s[uu][tl] = ph * mask[(size_t)b * T_ + t0 + tl];
        }
        __syncthreads();
        // acc += phi * ctx
        for (int tl = 0; tl < TC; ++tl) {
            float ph = phi_s[u_l][tl];
            float4 c0 = ((const float4*)(&ctx_s[tl][0]))[g];
            acc[0] += ph * c0.x; acc[1] += ph * c0.y;
            acc[2] += ph * c0.z; acc[3] += ph * c0.w;
        }
    }

    float* orow = out + ((size_t)b * U_ + u0 + u_l) * D_;
    *(float4*)(orow + 4 * g) = make_float4(acc[0], acc[1], acc[2], acc[3]);
}

extern "C" void kernel_launch(void* const* d_in, const int* in_sizes, int n_in,
                              void* d_out, int out_size, void* d_ws, size_t ws_size,
                              hipStream_t stream) {
    const float* h_t  = (const float*)d_in[0];
    const float* ctx  = (const float*)d_in[1];
    const float* mask = (const float*)d_in[2];
    const float* W    = (const float*)d_in[3];
    const float* bias = (const float*)d_in[4];
    float* out = (float*)d_out;

    unsigned* bars = (unsigned*)d_ws;                 // 4 counters in first 256 B
    float* alpha = (float*)((char*)d_ws + 256);
    const size_t NPARAM = (size_t)B_ * U_ * K_;       // 40960
    float* beta  = alpha + NPARAM;
    float* kinc  = beta + NPARAM;                     // becomes kappa after scan

    hipMemsetAsync(d_ws, 0, 256, stream);             // reset barrier state
    fused_kernel<<<dim3(NBLK), dim3(NTHR), 0, stream>>>(
        h_t, ctx, mask, W, bias, out, alpha, beta, kinc, bars);
}

// Round 4
// 43.726 us; speedup vs baseline: 5.1311x; 5.1311x over previous
//
#include <hip/hip_runtime.h>
#include <math.h>

#define B_ 8
#define U_ 512
#define T_ 1024
#define H_ 512
#define D_ 128
#define K_ 10

#define UT 8      // u rows per attend block / scan tile size
#define TC 64     // t chunk size
#define NTILES 64 // U_/UT

// ---------------- Kernel A: params + tile-local kappa scans -----------------
// Grid 256 blocks x 256 threads. Wave = 4 rows x 16 column-pairs.
// Lane (rr=lane>>4, jp=lane&15): computes p[row, j=2jp..2jp+1] = exp(h.W + b).
// jp 0-4 -> alpha, 5-9 -> beta, 10-14 -> kinc (x0.2, to LDS for tile scan).
// Then 160 threads produce L (tile-local inclusive scan) and T (tile totals).
__global__ __launch_bounds__(256)
void prep_kernel(const float* __restrict__ h_t,
                 const float* __restrict__ W,
                 const float* __restrict__ bias,
                 float* __restrict__ alpha,
                 float* __restrict__ beta,
                 float* __restrict__ L,     // [B*U][K] tile-local inclusive sums
                 float* __restrict__ T) {   // [B][NTILES][K] tile totals
    __shared__ float kin_s[16][K_];

    int tid = threadIdx.x;
    int lane = tid & 63;
    int w = tid >> 6;
    int rr = lane >> 4;                 // 0..3
    int jp = lane & 15;                 // 0..15 (15 = pad lane)
    int jj = (jp < 15) ? (2 * jp) : 28; // safe column base for pad lane
    int rowloc = w * 4 + rr;            // 0..15
    int row = blockIdx.x * 16 + rowloc; // 0..4095

    const float4* h4 = (const float4*)(h_t + (size_t)row * H_);
    float ax = 0.f, ay = 0.f;
    #pragma unroll 4
    for (int i4 = 0; i4 < H_ / 4; ++i4) {
        float4 hv = h4[i4];
        const float* wp = W + (size_t)(4 * i4) * (3 * K_) + jj;
        float2 w0 = *(const float2*)(wp);
        float2 w1 = *(const float2*)(wp + 30);
        float2 w2 = *(const float2*)(wp + 60);
        float2 w3 = *(const float2*)(wp + 90);
        ax += hv.x * w0.x + hv.y * w1.x + hv.z * w2.x + hv.w * w3.x;
        ay += hv.x * w0.y + hv.y * w1.y + hv.z * w2.y + hv.w * w3.y;
    }
    float2 bv = *(const float2*)(bias + jj);
    float px = __expf(ax + bv.x);
    float py = __expf(ay + bv.y);

    if (jp < 5) {
        *(float2*)(alpha + (size_t)row * K_ + 2 * jp) = make_float2(px, py);
    } else if (jp < 10) {
        *(float2*)(beta + (size_t)row * K_ + (2 * jp - 10)) = make_float2(px, py);
    } else if (jp < 15) {
        *(float2*)(&kin_s[rowloc][2 * (jp - 10)]) = make_float2(0.2f * px, 0.2f * py);
    }
    __syncthreads();

    if (tid < 16 * K_) {
        int u_l = tid / K_;             // 0..15
        int k = tid % K_;               // 0..9
        int tb = u_l & ~(UT - 1);       // tile base within block
        float s = 0.f;
        for (int r = tb; r <= u_l; ++r) s += kin_s[r][k];
        int urow = blockIdx.x * 16 + u_l;
        L[(size_t)urow * K_ + k] = s;
        if ((u_l & (UT - 1)) == (UT - 1)) {
            int b = urow >> 9;                  // /U_
            int tile = (urow & (U_ - 1)) >> 3;  // /UT
            T[((size_t)b * NTILES + tile) * K_ + k] = s;
        }
    }
}

// ---------------- Kernel B: prefix combine + phi + masked matmul ------------
// Grid 512 blocks (64 tiles x 8 batches) x 256 threads.
__global__ __launch_bounds__(256)
void attend_kernel(const float* __restrict__ alpha,
                   const float* __restrict__ beta,
                   const float* __restrict__ L,
                   const float* __restrict__ T,
                   const float* __restrict__ ctx,
                   const float* __restrict__ mask,
                   float* __restrict__ out) {
    __shared__ float a_s[UT][K_], b_s[UT][K_], k_s[UT][K_];
    __shared__ float phi_s[UT][68];          // row stride 272B (16B-aligned)
    __shared__ float ctx_s[TC][D_];          // 32 KB
    __shared__ float red_lo[256], red_hi[256];

    int tid = threadIdx.x;
    int b = blockIdx.x >> 6;
    int mytile = blockIdx.x & 63;
    int u0 = mytile * UT;

    // header: reconstruct kappa = sum of preceding tile totals + local scan
    float lo = 1e30f, hi = -1e30f;
    if (tid < UT * K_) {
        int u_l = tid / K_, k = tid % K_;
        size_t idx = ((size_t)(b * U_) + u0 + u_l) * K_ + k;
        float pre = 0.f;
        const float* tp = T + ((size_t)b * NTILES) * K_ + k;
        for (int j = 0; j < mytile; ++j) pre += tp[(size_t)j * K_];
        float kv = pre + L[idx];
        float av = alpha[idx], bvv = beta[idx];
        a_s[u_l][k] = av; b_s[u_l][k] = bvv; k_s[u_l][k] = kv;
        float r = sqrtf(88.f / bvv);   // f32 exp underflow radius
        lo = kv - r; hi = kv + r;
    }
    red_lo[tid] = lo; red_hi[tid] = hi;
    __syncthreads();
    for (int s = 128; s > 0; s >>= 1) {
        if (tid < s) {
            red_lo[tid] = fminf(red_lo[tid], red_lo[tid + s]);
            red_hi[tid] = fmaxf(red_hi[tid], red_hi[tid + s]);
        }
        __syncthreads();
    }
    int t_begin = max(0, (int)floorf(red_lo[0]));
    int t_end   = min(T_, (int)ceilf(red_hi[0]) + 1);
    t_begin = (t_begin / TC) * TC;

    int u_l = tid >> 5;                  // 0..7
    int g   = tid & 31;                  // d block: 4g..4g+3
    float acc[4];
    #pragma unroll
    for (int i = 0; i < 4; ++i) acc[i] = 0.f;

    for (int t0 = t_begin; t0 < t_end; t0 += TC) {
        __syncthreads();
        // stage ctx chunk (coalesced float4)
        {
            const float4* src = (const float4*)(ctx + (((size_t)b * T_ + t0) * D_));
            float4* dst = (float4*)(&ctx_s[0][0]);
            #pragma unroll
            for (int i = 0; i < (TC * D_ / 4) / 256; ++i)
                dst[tid + 256 * i] = src[tid + 256 * i];
        }
        // phi: UT*TC = 512 values, 2 per thread
        #pragma unroll
        for (int i = 0; i < 2; ++i) {
            int lin = tid + 256 * i;
            int uu = lin >> 6;           // wave-uniform -> broadcast param reads
            int tl = lin & 63;
            float tf = (float)(t0 + tl);
            float ph = 0.f;
            #pragma unroll
            for (int k = 0; k < K_; ++k) {
                float d = k_s[uu][k] - tf;
                float x = b_s[uu][k] * d * d;
                ph += a_s[uu][k] * __expf(-x);
            }
            phi_s[uu][tl] = ph * mask[(size_t)b * T_ + t0 + tl];
        }
        __syncthreads();
        // acc += phi * ctx   (phi hoisted 4-wide)
        for (int tl4 = 0; tl4 < TC / 4; ++tl4) {
            float4 ph4 = *(const float4*)(&phi_s[u_l][4 * tl4]);
            #pragma unroll
            for (int q = 0; q < 4; ++q) {
                float ph = (q == 0) ? ph4.x : (q == 1) ? ph4.y : (q == 2) ? ph4.z : ph4.w;
                float4 c0 = ((const float4*)(&ctx_s[4 * tl4 + q][0]))[g];
                acc[0] += ph * c0.x; acc[1] += ph * c0.y;
                acc[2] += ph * c0.z; acc[3] += ph * c0.w;
            }
        }
    }

    float* orow = out + ((size_t)b * U_ + u0 + u_l) * D_;
    *(float4*)(orow + 4 * g) = make_float4(acc[0], acc[1], acc[2], acc[3]);
}

extern "C" void kernel_launch(void* const* d_in, const int* in_sizes, int n_in,
                              void* d_out, int out_size, void* d_ws, size_t ws_size,
                              hipStream_t stream) {
    const float* h_t  = (const float*)d_in[0];
    const float* ctx  = (const float*)d_in[1];
    const float* mask = (const float*)d_in[2];
    const float* W    = (const float*)d_in[3];
    const float* bias = (const float*)d_in[4];
    float* out = (float*)d_out;

    const size_t NPARAM = (size_t)B_ * U_ * K_;       // 40960
    float* alpha = (float*)d_ws;
    float* beta  = alpha + NPARAM;
    float* L     = beta + NPARAM;
    float* T     = L + NPARAM;                        // B*NTILES*K = 5120

    prep_kernel<<<dim3(256), dim3(256), 0, stream>>>(h_t, W, bias, alpha, beta, L, T);
    attend_kernel<<<dim3(512), dim3(256), 0, stream>>>(alpha, beta, L, T, ctx, mask, out);
}